// Round 5
// baseline (612.923 us; speedup 1.0000x reference)
//
#include <hip/hip_runtime.h>
#include <string.h>

// Problem constants
constexpr int cB = 64, cS = 512, cN = 512, cM = 128, cUNF = 6;
constexpr float cDELTA = 0.016666666666666666f;  // DT/UNFOLDS = 0.1/6

// r20: single-kernel, full-machine cooperative weight gather.
//   r19 post-mortem: k_fused ~50us; the 10MB weight/mask/probe gather ran on
//   32 CUs at ~280 GB/s aggregate (~9 GB/s/CU) -> ~38us latency-bound tail.
//   Fix: grid = 256 blocks (1/CU, co-residency guaranteed: 16 waves <= 32,
//   64.5KB LDS <= 160KB, launch_bounds(1024,1) => VGPR <= 128). All blocks
//   gather 1/256 of the sources (2 elems x 5 arrays/thread, independent
//   loads) and write a 2MB packed f16 fragment table to ws with coalesced
//   dword stores; per-block done-slot signals completion (poison-negative
//   trick). Helper blocks (>=32) exit; compute blocks 0..31 poll the 256
//   done flags, then burst-copy their 64KB slice to LDS via
//   global_load_dwordx4 sc0 sc1 (bypass possibly-stale per-XCD L2 -- no
//   dispatch boundary inside one kernel). Sensory MFMA + 6 unfolds +
//   f16 gated exchange + generation-slot barrier unchanged from r19.
constexpr int JT   = 16;            // j-columns per compute block
constexpr int NCB  = cN / JT;       // 32 compute blocks
constexpr int NBLK = 256;           // total blocks (1 per CU)
constexpr int NT   = 1024;          // 16 waves
constexpr int NCW  = 4;             // compute waves (wave mt owns batch tile)
constexpr int SLOT_STRIDE = 16;     // ints; 64 B slot spacing

// ws layout (float offsets)
constexpr size_t OFF_V0   = 0;                            // [B][N] f32 ping
constexpr size_t OFF_V1   = (size_t)cB * cN;              // [B][N] f32 pong
constexpr size_t OFF_H0   = OFF_V1 + (size_t)cB * cN;     // [B][N] f16 ping
constexpr size_t OFF_H1   = OFF_H0 + (size_t)cB * cN / 2; // [B][N] f16 pong
constexpr size_t OFF_SLOT = OFF_H1 + (size_t)cB * cN / 2; // 32 slots x 16 ints
constexpr size_t OFF_DONE = OFF_SLOT + 128;               // 256 slots x 16 ints
constexpr size_t OFF_BAD  = OFF_DONE + 1024;              // 64 ints
constexpr size_t OFF_PK   = 131072;                       // packed table, 2 MB
// packed table: per jt a 64KB LDS image: [mat4][1024 frags][16B], mat4 =
// {recE, recW, sensE, sensW}; frag = kk*64 + lg*16 + lr; elem t at byte 2t.

typedef _Float16 half8 __attribute__((ext_vector_type(8)));
typedef float    floatx4 __attribute__((ext_vector_type(4)));

__device__ __forceinline__ float clamp01(float x) {
    return __builtin_amdgcn_fmed3f(x, 0.0f, 1.0f);
}

__device__ __forceinline__ unsigned pack2h(float lo, float hi) {
    _Float16 l = (_Float16)lo, h = (_Float16)hi;
    unsigned short ls, hs;
    memcpy(&ls, &l, 2); memcpy(&hs, &h, 2);
    return (unsigned)ls | ((unsigned)hs << 16);
}

__global__ __launch_bounds__(NT, 1)
void k_fused(const float* __restrict__ inputs, const float* __restrict__ states,
             const float* __restrict__ tau,    const float* __restrict__ bias,
             const float* __restrict__ erev,   const float* __restrict__ wgt,
             const float* __restrict__ sigma,  const float* __restrict__ mu,
             const float* __restrict__ serev,  const float* __restrict__ swgt,
             const float* __restrict__ ssigma, const float* __restrict__ smu,
             const float* __restrict__ mask,   const float* __restrict__ smask,
             const float* __restrict__ inw,    const float* __restrict__ inb,
             const float* __restrict__ outw,   const float* __restrict__ outb,
             float* __restrict__ out, float* __restrict__ ws)
{
    float* v0 = ws + OFF_V0;
    float* v1 = ws + OFF_V1;
    _Float16* h0 = (_Float16*)(ws + OFF_H0);
    _Float16* h1 = (_Float16*)(ws + OFF_H1);
    int* slots = (int*)(ws + OFF_SLOT);
    int* done  = (int*)(ws + OFF_DONE);
    int* badf  = (int*)(ws + OFF_BAD);
    unsigned* pk = (unsigned*)(ws + OFF_PK);

    const int tid = threadIdx.x, blk = blockIdx.x;

    // ================= phase 1: cooperative gather (all 256 blocks) ========
    {
        const unsigned g = (unsigned)blk * NT + tid;     // [0, 262144)
        const int lr  = g & 15;           // column within j-tile
        const int qp  = (g >> 4) & 3;     // t-pair (t = 2qp, 2qp+1)
        const int lg2 = (g >> 6) & 3;     // k-group
        const int kk2 = (g >> 8) & 15;    // K-step
        const int jt2 = (g >> 12) & 31;   // j-tile
        const int m2  = (g >> 17) & 1;    // 0 = recurrent, 1 = sensory

        const float* E  = m2 ? serev  : erev;
        const float* W  = m2 ? swgt   : wgt;
        const float* SG = m2 ? ssigma : sigma;
        const float* MU = m2 ? smu    : mu;
        const float* MK = m2 ? smask  : mask;

        const int j  = jt2 * JT + lr;
        const int i0 = kk2 * 32 + lg2 * 8 + qp * 2;
        const size_t o0 = (size_t)i0 * cN + j, o1 = o0 + cN;
        const float e0 = E[o0],  e1 = E[o1];
        const float w0 = W[o0],  w1 = W[o1];
        const float m0 = MK[o0], m1 = MK[o1];
        const float s0 = SG[o0], s1 = SG[o1];
        const float u0 = MU[o0], u1 = MU[o1];
        const bool bad = (m0 != 0.f && (s0 != 0.5f || u0 != 0.5f)) ||
                         (m1 != 0.f && (s1 != 0.5f || u1 != 0.5f));

        const unsigned ed = pack2h(e0 * m0, e1 * m1);
        const unsigned wd = pack2h(w0 * m0, w1 * m1);
        const int frag = kk2 * 64 + lg2 * 16 + lr;
        unsigned* base = pk + (size_t)jt2 * 16384 + (m2 * 2) * 4096 + frag * 4 + qp;
        __hip_atomic_store(base,        ed, __ATOMIC_RELAXED, __HIP_MEMORY_SCOPE_AGENT);
        __hip_atomic_store(base + 4096, wd, __ATOMIC_RELAXED, __HIP_MEMORY_SCOPE_AGENT);
        if (bad)
            __hip_atomic_store(&badf[m2 * 32 + jt2], 1,
                               __ATOMIC_RELAXED, __HIP_MEMORY_SCOPE_AGENT);
    }
    __syncthreads();                       // vmcnt(0) drain of all gather stores
    if (tid == 0)
        __hip_atomic_store(&done[blk * SLOT_STRIDE], 1,
                           __ATOMIC_RELAXED, __HIP_MEMORY_SCOPE_AGENT);
    if (blk >= NCB) return;                // helper blocks done

    // ================= phase 2: compute blocks 0..31 =======================
    const int j0   = blk * JT;
    const int lane = tid & 63;
    const int wv   = tid >> 6;          // wave id 0..15; compute waves: wv < 4
    const int mt   = wv;                // M-tile (batch group of 16)
    const int lr   = lane & 15;
    const int lg   = lane >> 4;
    const int bj   = j0 + lr;           // this lane's output column j (B/C)
    const int arow = mt * 16 + lr;      // A-fragment row (batch)
    const int kbase = lg * 8;
    const int cb0  = mt * 16 + lg * 4;  // first owned batch row (C mapping)

    int* mySlot = slots + blk * SLOT_STRIDE;

    __shared__ _Float16 Hlds[32768];    // 64 KB fragment table (LDS image)
    const half8* hfr = (const half8*)Hlds;

    // ---- per-lane owned cells (compute waves) ----
    float vold[4] = {0.f, 0.f, 0.f, 0.f};
    float tau_j = 0.f, bias_j = 0.f, ow = 0.f, ob = 0.f;
    if (wv < NCW) {
#pragma unroll
        for (int r = 0; r < 4; ++r)
            vold[r] = states[(size_t)(cb0 + r) * cN + bj];
        tau_j  = tau[bj];
        bias_j = bias[bj];
        if (bj >= cN - cM) { ow = outw[bj - (cN - cM)]; ob = outb[bj - (cN - cM)]; }
    }

    // ---- wait for all 256 gather-done flags (parallel polls) ----
    if (tid < NBLK) {
        const int* sl = done + tid * SLOT_STRIDE;
        while (__hip_atomic_load(sl, __ATOMIC_RELAXED, __HIP_MEMORY_SCOPE_AGENT) < 1)
            __builtin_amdgcn_s_sleep(1);
    }
    __syncthreads();

    const bool fastR = (__hip_atomic_load(&badf[blk], __ATOMIC_RELAXED,
                                          __HIP_MEMORY_SCOPE_AGENT) != 1);
    const bool fastS = (__hip_atomic_load(&badf[32 + blk], __ATOMIC_RELAXED,
                                          __HIP_MEMORY_SCOPE_AGENT) != 1);

    // ---- LDS fill: 64KB slice, 4 x 16B burst loads (bypass stale L1/L2) ----
    {
        const uint4* src = (const uint4*)pk + (size_t)blk * 4096;
        floatx4 tmp[4];
#pragma unroll
        for (int r = 0; r < 4; ++r)
            asm volatile("global_load_dwordx4 %0, %1, off sc0 sc1"
                         : "=v"(tmp[r]) : "v"(src + r * 1024 + tid) : "memory");
        asm volatile("s_waitcnt vmcnt(0)" ::: "memory");
        __builtin_amdgcn_sched_barrier(0);   // rule #18
#pragma unroll
        for (int r = 0; r < 4; ++r)
            ((uint4*)Hlds)[r * 1024 + tid] = __builtin_bit_cast(uint4, tmp[r]);
    }
    __syncthreads();

    // ---- sensory reduction -> srb (s_rev + bias), swv (s_w) ----
    float srb[4] = {0.f, 0.f, 0.f, 0.f}, swv[4] = {0.f, 0.f, 0.f, 0.f};
    if (wv < NCW) {
        if (fastS) {
            floatx4 aR = {0.f, 0.f, 0.f, 0.f}, aW = {0.f, 0.f, 0.f, 0.f};
#pragma unroll
            for (int kk = 0; kk < 16; ++kk) {
                const int off = kk * 32 + kbase;
                const float4 xa = *(const float4*)(inputs + (size_t)arow * cS + off);
                const float4 xb = *(const float4*)(inputs + (size_t)arow * cS + off + 4);
                const float4 wa = *(const float4*)(inw + off);
                const float4 wb = *(const float4*)(inw + off + 4);
                const float4 ba = *(const float4*)(inb + off);
                const float4 bb = *(const float4*)(inb + off + 4);
                half8 ax;
                ax[0] = (_Float16)clamp01(fmaf(xa.x, wa.x, ba.x));
                ax[1] = (_Float16)clamp01(fmaf(xa.y, wa.y, ba.y));
                ax[2] = (_Float16)clamp01(fmaf(xa.z, wa.z, ba.z));
                ax[3] = (_Float16)clamp01(fmaf(xa.w, wa.w, ba.w));
                ax[4] = (_Float16)clamp01(fmaf(xb.x, wb.x, bb.x));
                ax[5] = (_Float16)clamp01(fmaf(xb.y, wb.y, bb.y));
                ax[6] = (_Float16)clamp01(fmaf(xb.z, wb.z, bb.z));
                ax[7] = (_Float16)clamp01(fmaf(xb.w, wb.w, bb.w));
                aR = __builtin_amdgcn_mfma_f32_16x16x32_f16(ax, hfr[2048 + kk * 64 + lane], aR, 0, 0, 0);
                aW = __builtin_amdgcn_mfma_f32_16x16x32_f16(ax, hfr[3072 + kk * 64 + lane], aW, 0, 0, 0);
            }
#pragma unroll
            for (int r = 0; r < 4; ++r) { srb[r] = aR[r] + bias_j; swv[r] = aW[r]; }
        } else {
            // general sensory path (slow, correct, unexercised by the bench)
            float sr4[4] = {0,0,0,0}, sw4[4] = {0,0,0,0};
            for (int s = 0; s < cS; ++s) {
                size_t o = (size_t)s * cN + bj;
                float mk = smask[o];
                float sg = ssigma[o];
                float a  = 0.5f / sg;
                float c  = fmaf(-smu[o], a, 0.5f);
                float ee = serev[o] * mk, ww = swgt[o] * mk;
                float iw = inw[s], ib = inb[s];
#pragma unroll
                for (int r = 0; r < 4; ++r) {
                    float x = fmaf(inputs[(size_t)(cb0 + r) * cS + s], iw, ib);
                    float g = clamp01(fmaf(x, a, c));
                    sr4[r] = fmaf(g, ee, sr4[r]);
                    sw4[r] = fmaf(g, ww, sw4[r]);
                }
            }
#pragma unroll
            for (int r = 0; r < 4; ++r) { srb[r] = sr4[r] + bias_j; swv[r] = sw4[r]; }
        }
    }

    // ---- 6 unfolds; unfold 0 reads `states` directly ----
    for (int u = 0; u < cUNF; ++u) {
        const float*    vRp = (u == 0) ? states : ((u & 1) ? v0 : v1);
        const _Float16* hRp = (u & 1) ? h0 : h1;   // valid for u >= 1

        float sumE[4], sumW[4];
        if (wv < NCW) {
            if (fastR) {
                floatx4 aE = {0.f, 0.f, 0.f, 0.f}, aWc = {0.f, 0.f, 0.f, 0.f};
                if (u == 0) {
                    // plain cached float4 loads from states (pure input)
                    const float* vrow = states + (size_t)arow * cN + kbase;
#pragma unroll
                    for (int kk = 0; kk < 16; ++kk) {
                        const float4 va = *(const float4*)(vrow + kk * 32);
                        const float4 vb = *(const float4*)(vrow + kk * 32 + 4);
                        half8 a8;
                        a8[0] = (_Float16)clamp01(va.x);
                        a8[1] = (_Float16)clamp01(va.y);
                        a8[2] = (_Float16)clamp01(va.z);
                        a8[3] = (_Float16)clamp01(va.w);
                        a8[4] = (_Float16)clamp01(vb.x);
                        a8[5] = (_Float16)clamp01(vb.y);
                        a8[6] = (_Float16)clamp01(vb.z);
                        a8[7] = (_Float16)clamp01(vb.w);
                        aE  = __builtin_amdgcn_mfma_f32_16x16x32_f16(a8, hfr[kk * 64 + lane], aE,  0, 0, 0);
                        aWc = __builtin_amdgcn_mfma_f32_16x16x32_f16(a8, hfr[1024 + kk * 64 + lane], aWc, 0, 0, 0);
                    }
                } else {
                    // A-gather: 16 pipelined 16B gated-f16 loads, ONE waitcnt.
                    floatx4 raw[16];
                    const _Float16* hrow = hRp + (size_t)arow * cN + kbase;
#pragma unroll
                    for (int kk = 0; kk < 16; ++kk)
                        asm volatile("global_load_dwordx4 %0, %1, off offset:%2 sc0 sc1"
                                     : "=v"(raw[kk]) : "v"(hrow), "n"(kk * 64) : "memory");
                    asm volatile("s_waitcnt vmcnt(0)" ::: "memory");
                    __builtin_amdgcn_sched_barrier(0);   // rule #18
#pragma unroll
                    for (int kk = 0; kk < 16; ++kk) {
                        const half8 a8 = __builtin_bit_cast(half8, raw[kk]);
                        aE  = __builtin_amdgcn_mfma_f32_16x16x32_f16(a8, hfr[kk * 64 + lane], aE,  0, 0, 0);
                        aWc = __builtin_amdgcn_mfma_f32_16x16x32_f16(a8, hfr[1024 + kk * 64 + lane], aWc, 0, 0, 0);
                    }
                }
#pragma unroll
                for (int r = 0; r < 4; ++r) { sumE[r] = aE[r]; sumW[r] = aWc[r]; }
            } else {
                // general recurrent path (slow, correct): reads raw f32 v
                float r4[4] = {0,0,0,0}, w4[4] = {0,0,0,0};
                for (int i = 0; i < cN; ++i) {
                    size_t o = (size_t)i * cN + bj;
                    float mk = mask[o];
                    float sg = sigma[o];
                    float a  = 0.5f / sg;
                    float c  = fmaf(-mu[o], a, 0.5f);
                    float ee = erev[o] * mk, ww = wgt[o] * mk;
#pragma unroll
                    for (int r = 0; r < 4; ++r) {
                        float vi = __hip_atomic_load(&vRp[(size_t)(cb0 + r) * cN + i],
                                                     __ATOMIC_RELAXED, __HIP_MEMORY_SCOPE_AGENT);
                        float g = clamp01(fmaf(vi, a, c));
                        r4[r] = fmaf(g, ee, r4[r]);
                        w4[r] = fmaf(g, ww, w4[r]);
                    }
                }
#pragma unroll
                for (int r = 0; r < 4; ++r) { sumE[r] = r4[r]; sumW[r] = w4[r]; }
            }

            // v update for owned cells (all state in registers)
#pragma unroll
            for (int r = 0; r < 4; ++r) {
                float rr   = sumE[r] + srb[r];
                float wsum = sumW[r] + swv[r];
                float k    = 1.0f / (1.0f + wsum);
                float taun = tau_j * k;
                float inv  = 1.0f / (taun + cDELTA);
                float vn   = (taun * inv) * vold[r] + (cDELTA * inv) * k * rr;
                vold[r] = vn;
            }
        }

        if (u < cUNF - 1) {
            // publish v(u+1) (raw f32 for slow readers, gated f16 for fast);
            // generation barrier gen u+1 (1..5). Safety: slot store follows a
            // __syncthreads that drains all prior memory ops (incl. this
            // block's reads of the buffer being recycled).
            if (wv < NCW) {
                float*    vWp = (u & 1) ? v1 : v0;
                _Float16* hWp = (u & 1) ? h1 : h0;
#pragma unroll
                for (int r = 0; r < 4; ++r) {
                    __hip_atomic_store(&vWp[(size_t)(cb0 + r) * cN + bj], vold[r],
                                       __ATOMIC_RELAXED, __HIP_MEMORY_SCOPE_AGENT);
                    _Float16 g = (_Float16)clamp01(vold[r]);
                    unsigned short gs;
                    memcpy(&gs, &g, 2);
                    unsigned int gi = gs;
                    asm volatile("global_store_short %0, %1, off sc0 sc1"
                                 :: "v"(hWp + (size_t)(cb0 + r) * cN + bj), "v"(gi)
                                 : "memory");
                }
            }
            __syncthreads();               // vmcnt(0) drain of the publishes
            if (tid == 0)
                __hip_atomic_store(mySlot, u + 1,
                                   __ATOMIC_RELAXED, __HIP_MEMORY_SCOPE_AGENT);
            if (tid < NCB) {
                const int* sl = slots + tid * SLOT_STRIDE;
                while (__hip_atomic_load(sl, __ATOMIC_RELAXED,
                                         __HIP_MEMORY_SCOPE_AGENT) < u + 1)
                    __builtin_amdgcn_s_sleep(1);
            }
            __syncthreads();
        }
    }

    // ---- epilogue: final v + mapped outputs ----
    if (wv < NCW) {
        float* vout = out + (size_t)cB * cM;
#pragma unroll
        for (int r = 0; r < 4; ++r) {
            int b = cb0 + r;
            vout[(size_t)b * cN + bj] = vold[r];
            if (bj >= cN - cM)
                out[(size_t)b * cM + (bj - (cN - cM))] = fmaf(vold[r], ow, ob);
        }
    }
}

extern "C" void kernel_launch(void* const* d_in, const int* in_sizes, int n_in,
                              void* d_out, int out_size, void* d_ws, size_t ws_size,
                              hipStream_t stream)
{
    const float* inputs = (const float*)d_in[0];
    const float* states = (const float*)d_in[1];
    const float* tau    = (const float*)d_in[2];
    const float* bias   = (const float*)d_in[3];
    const float* erev   = (const float*)d_in[4];
    const float* wgt    = (const float*)d_in[5];
    const float* sigma  = (const float*)d_in[6];
    const float* mu     = (const float*)d_in[7];
    const float* serev  = (const float*)d_in[8];
    const float* swgt   = (const float*)d_in[9];
    const float* ssigma = (const float*)d_in[10];
    const float* smu    = (const float*)d_in[11];
    const float* mask   = (const float*)d_in[12];
    const float* smask  = (const float*)d_in[13];
    const float* inw    = (const float*)d_in[14];
    const float* inb    = (const float*)d_in[15];
    const float* outw   = (const float*)d_in[16];
    const float* outb   = (const float*)d_in[17];
    float* out = (float*)d_out;
    float* ws  = (float*)d_ws;

    // Single dispatch: 256 blocks x 1024 threads, exactly 1 block/CU
    // (16 waves <= 32, 64.5KB LDS <= 160KB, VGPR <= 128 via launch_bounds)
    // -> all blocks co-resident; internal spin barriers cannot deadlock.
    // All generation slots start from harness poison (negative as int).
    k_fused<<<NBLK, NT, 0, stream>>>(inputs, states, tau, bias, erev, wgt,
                                     sigma, mu, serev, swgt, ssigma, smu,
                                     mask, smask, inw, inb, outw, outb,
                                     out, ws);
}

// Round 6
// 131.333 us; speedup vs baseline: 4.6670x; 4.6670x over previous
//
#include <hip/hip_runtime.h>
#include <string.h>

// Problem constants
constexpr int cB = 64, cS = 512, cN = 512, cM = 128, cUNF = 6;
constexpr float cDELTA = 0.016666666666666666f;  // DT/UNFOLDS = 0.1/6

// r21: r20 with the workspace-layout aliasing bug fixed.
//   r20 post-mortem: 557us, VALUBusy 0.38%, 33 GB/s, perfectly repeatable =
//   serial-path signature. OFF_DONE/OFF_BAD were sized for 128/1024 ints but
//   the regions need 512/4096: done[64..67] flag writes (=1) aliased onto
//   badf[0]/badf[16]/badf[32]/badf[48], flipping blocks 0 and 16 onto the
//   general (serial, correct) fallback paths -- ~550us while 30 blocks
//   waited at the generation barriers. The cooperative gather + packed
//   table + MFMA fast path were exercised by the other 30 blocks and are
//   correct. Fix: OFF_DONE = OFF_SLOT + 512, OFF_BAD = OFF_DONE + 4096
//   (also removes the done->slot gen-1 aliasing race).
constexpr int JT   = 16;            // j-columns per compute block
constexpr int NCB  = cN / JT;       // 32 compute blocks
constexpr int NBLK = 256;           // total blocks (1 per CU)
constexpr int NT   = 1024;          // 16 waves
constexpr int NCW  = 4;             // compute waves (wave mt owns batch tile)
constexpr int SLOT_STRIDE = 16;     // ints; 64 B slot spacing

// ws layout (float offsets)
constexpr size_t OFF_V0   = 0;                            // [B][N] f32 ping
constexpr size_t OFF_V1   = (size_t)cB * cN;              // [B][N] f32 pong
constexpr size_t OFF_H0   = OFF_V1 + (size_t)cB * cN;     // [B][N] f16 ping
constexpr size_t OFF_H1   = OFF_H0 + (size_t)cB * cN / 2; // [B][N] f16 pong
constexpr size_t OFF_SLOT = OFF_H1 + (size_t)cB * cN / 2; // 32 slots x 16 ints = 512
constexpr size_t OFF_DONE = OFF_SLOT + 512;               // 256 slots x 16 ints = 4096
constexpr size_t OFF_BAD  = OFF_DONE + 4096;              // 64 ints
constexpr size_t OFF_PK   = 131072;                       // packed table, 2 MB
static_assert(OFF_BAD + 64 <= OFF_PK, "control region must not alias packed table");
// packed table: per jt a 64KB LDS image: [mat4][1024 frags][16B], mat4 =
// {recE, recW, sensE, sensW}; frag = kk*64 + lg*16 + lr; elem t at byte 2t.

typedef _Float16 half8 __attribute__((ext_vector_type(8)));
typedef float    floatx4 __attribute__((ext_vector_type(4)));

__device__ __forceinline__ float clamp01(float x) {
    return __builtin_amdgcn_fmed3f(x, 0.0f, 1.0f);
}

__device__ __forceinline__ unsigned pack2h(float lo, float hi) {
    _Float16 l = (_Float16)lo, h = (_Float16)hi;
    unsigned short ls, hs;
    memcpy(&ls, &l, 2); memcpy(&hs, &h, 2);
    return (unsigned)ls | ((unsigned)hs << 16);
}

__global__ __launch_bounds__(NT, 1)
void k_fused(const float* __restrict__ inputs, const float* __restrict__ states,
             const float* __restrict__ tau,    const float* __restrict__ bias,
             const float* __restrict__ erev,   const float* __restrict__ wgt,
             const float* __restrict__ sigma,  const float* __restrict__ mu,
             const float* __restrict__ serev,  const float* __restrict__ swgt,
             const float* __restrict__ ssigma, const float* __restrict__ smu,
             const float* __restrict__ mask,   const float* __restrict__ smask,
             const float* __restrict__ inw,    const float* __restrict__ inb,
             const float* __restrict__ outw,   const float* __restrict__ outb,
             float* __restrict__ out, float* __restrict__ ws)
{
    float* v0 = ws + OFF_V0;
    float* v1 = ws + OFF_V1;
    _Float16* h0 = (_Float16*)(ws + OFF_H0);
    _Float16* h1 = (_Float16*)(ws + OFF_H1);
    int* slots = (int*)(ws + OFF_SLOT);
    int* done  = (int*)(ws + OFF_DONE);
    int* badf  = (int*)(ws + OFF_BAD);
    unsigned* pk = (unsigned*)(ws + OFF_PK);

    const int tid = threadIdx.x, blk = blockIdx.x;

    // ================= phase 1: cooperative gather (all 256 blocks) ========
    {
        const unsigned g = (unsigned)blk * NT + tid;     // [0, 262144)
        const int lr  = g & 15;           // column within j-tile
        const int qp  = (g >> 4) & 3;     // t-pair (t = 2qp, 2qp+1)
        const int lg2 = (g >> 6) & 3;     // k-group
        const int kk2 = (g >> 8) & 15;    // K-step
        const int jt2 = (g >> 12) & 31;   // j-tile
        const int m2  = (g >> 17) & 1;    // 0 = recurrent, 1 = sensory

        const float* E  = m2 ? serev  : erev;
        const float* W  = m2 ? swgt   : wgt;
        const float* SG = m2 ? ssigma : sigma;
        const float* MU = m2 ? smu    : mu;
        const float* MK = m2 ? smask  : mask;

        const int j  = jt2 * JT + lr;
        const int i0 = kk2 * 32 + lg2 * 8 + qp * 2;
        const size_t o0 = (size_t)i0 * cN + j, o1 = o0 + cN;
        const float e0 = E[o0],  e1 = E[o1];
        const float w0 = W[o0],  w1 = W[o1];
        const float m0 = MK[o0], m1 = MK[o1];
        const float s0 = SG[o0], s1 = SG[o1];
        const float u0 = MU[o0], u1 = MU[o1];
        const bool bad = (m0 != 0.f && (s0 != 0.5f || u0 != 0.5f)) ||
                         (m1 != 0.f && (s1 != 0.5f || u1 != 0.5f));

        const unsigned ed = pack2h(e0 * m0, e1 * m1);
        const unsigned wd = pack2h(w0 * m0, w1 * m1);
        const int frag = kk2 * 64 + lg2 * 16 + lr;
        unsigned* base = pk + (size_t)jt2 * 16384 + (m2 * 2) * 4096 + frag * 4 + qp;
        __hip_atomic_store(base,        ed, __ATOMIC_RELAXED, __HIP_MEMORY_SCOPE_AGENT);
        __hip_atomic_store(base + 4096, wd, __ATOMIC_RELAXED, __HIP_MEMORY_SCOPE_AGENT);
        if (bad)
            __hip_atomic_store(&badf[m2 * 32 + jt2], 1,
                               __ATOMIC_RELAXED, __HIP_MEMORY_SCOPE_AGENT);
    }
    __syncthreads();                       // vmcnt(0) drain of all gather stores
    if (tid == 0)
        __hip_atomic_store(&done[blk * SLOT_STRIDE], 1,
                           __ATOMIC_RELAXED, __HIP_MEMORY_SCOPE_AGENT);
    if (blk >= NCB) return;                // helper blocks done

    // ================= phase 2: compute blocks 0..31 =======================
    const int j0   = blk * JT;
    const int lane = tid & 63;
    const int wv   = tid >> 6;          // wave id 0..15; compute waves: wv < 4
    const int mt   = wv;                // M-tile (batch group of 16)
    const int lr   = lane & 15;
    const int lg   = lane >> 4;
    const int bj   = j0 + lr;           // this lane's output column j (B/C)
    const int arow = mt * 16 + lr;      // A-fragment row (batch)
    const int kbase = lg * 8;
    const int cb0  = mt * 16 + lg * 4;  // first owned batch row (C mapping)

    int* mySlot = slots + blk * SLOT_STRIDE;

    __shared__ _Float16 Hlds[32768];    // 64 KB fragment table (LDS image)
    const half8* hfr = (const half8*)Hlds;

    // ---- per-lane owned cells (compute waves) ----
    float vold[4] = {0.f, 0.f, 0.f, 0.f};
    float tau_j = 0.f, bias_j = 0.f, ow = 0.f, ob = 0.f;
    if (wv < NCW) {
#pragma unroll
        for (int r = 0; r < 4; ++r)
            vold[r] = states[(size_t)(cb0 + r) * cN + bj];
        tau_j  = tau[bj];
        bias_j = bias[bj];
        if (bj >= cN - cM) { ow = outw[bj - (cN - cM)]; ob = outb[bj - (cN - cM)]; }
    }

    // ---- wait for all 256 gather-done flags (parallel polls) ----
    if (tid < NBLK) {
        const int* sl = done + tid * SLOT_STRIDE;
        while (__hip_atomic_load(sl, __ATOMIC_RELAXED, __HIP_MEMORY_SCOPE_AGENT) < 1)
            __builtin_amdgcn_s_sleep(1);
    }
    __syncthreads();

    const bool fastR = (__hip_atomic_load(&badf[blk], __ATOMIC_RELAXED,
                                          __HIP_MEMORY_SCOPE_AGENT) != 1);
    const bool fastS = (__hip_atomic_load(&badf[32 + blk], __ATOMIC_RELAXED,
                                          __HIP_MEMORY_SCOPE_AGENT) != 1);

    // ---- LDS fill: 64KB slice, 4 x 16B burst loads (bypass stale L1/L2) ----
    {
        const uint4* src = (const uint4*)pk + (size_t)blk * 4096;
        floatx4 tmp[4];
#pragma unroll
        for (int r = 0; r < 4; ++r)
            asm volatile("global_load_dwordx4 %0, %1, off sc0 sc1"
                         : "=v"(tmp[r]) : "v"(src + r * 1024 + tid) : "memory");
        asm volatile("s_waitcnt vmcnt(0)" ::: "memory");
        __builtin_amdgcn_sched_barrier(0);   // rule #18
#pragma unroll
        for (int r = 0; r < 4; ++r)
            ((uint4*)Hlds)[r * 1024 + tid] = __builtin_bit_cast(uint4, tmp[r]);
    }
    __syncthreads();

    // ---- sensory reduction -> srb (s_rev + bias), swv (s_w) ----
    float srb[4] = {0.f, 0.f, 0.f, 0.f}, swv[4] = {0.f, 0.f, 0.f, 0.f};
    if (wv < NCW) {
        if (fastS) {
            floatx4 aR = {0.f, 0.f, 0.f, 0.f}, aW = {0.f, 0.f, 0.f, 0.f};
#pragma unroll
            for (int kk = 0; kk < 16; ++kk) {
                const int off = kk * 32 + kbase;
                const float4 xa = *(const float4*)(inputs + (size_t)arow * cS + off);
                const float4 xb = *(const float4*)(inputs + (size_t)arow * cS + off + 4);
                const float4 wa = *(const float4*)(inw + off);
                const float4 wb = *(const float4*)(inw + off + 4);
                const float4 ba = *(const float4*)(inb + off);
                const float4 bb = *(const float4*)(inb + off + 4);
                half8 ax;
                ax[0] = (_Float16)clamp01(fmaf(xa.x, wa.x, ba.x));
                ax[1] = (_Float16)clamp01(fmaf(xa.y, wa.y, ba.y));
                ax[2] = (_Float16)clamp01(fmaf(xa.z, wa.z, ba.z));
                ax[3] = (_Float16)clamp01(fmaf(xa.w, wa.w, ba.w));
                ax[4] = (_Float16)clamp01(fmaf(xb.x, wb.x, bb.x));
                ax[5] = (_Float16)clamp01(fmaf(xb.y, wb.y, bb.y));
                ax[6] = (_Float16)clamp01(fmaf(xb.z, wb.z, bb.z));
                ax[7] = (_Float16)clamp01(fmaf(xb.w, wb.w, bb.w));
                aR = __builtin_amdgcn_mfma_f32_16x16x32_f16(ax, hfr[2048 + kk * 64 + lane], aR, 0, 0, 0);
                aW = __builtin_amdgcn_mfma_f32_16x16x32_f16(ax, hfr[3072 + kk * 64 + lane], aW, 0, 0, 0);
            }
#pragma unroll
            for (int r = 0; r < 4; ++r) { srb[r] = aR[r] + bias_j; swv[r] = aW[r]; }
        } else {
            // general sensory path (slow, correct, unexercised by the bench)
            float sr4[4] = {0,0,0,0}, sw4[4] = {0,0,0,0};
            for (int s = 0; s < cS; ++s) {
                size_t o = (size_t)s * cN + bj;
                float mk = smask[o];
                float sg = ssigma[o];
                float a  = 0.5f / sg;
                float c  = fmaf(-smu[o], a, 0.5f);
                float ee = serev[o] * mk, ww = swgt[o] * mk;
                float iw = inw[s], ib = inb[s];
#pragma unroll
                for (int r = 0; r < 4; ++r) {
                    float x = fmaf(inputs[(size_t)(cb0 + r) * cS + s], iw, ib);
                    float g = clamp01(fmaf(x, a, c));
                    sr4[r] = fmaf(g, ee, sr4[r]);
                    sw4[r] = fmaf(g, ww, sw4[r]);
                }
            }
#pragma unroll
            for (int r = 0; r < 4; ++r) { srb[r] = sr4[r] + bias_j; swv[r] = sw4[r]; }
        }
    }

    // ---- 6 unfolds; unfold 0 reads `states` directly ----
    for (int u = 0; u < cUNF; ++u) {
        const float*    vRp = (u == 0) ? states : ((u & 1) ? v0 : v1);
        const _Float16* hRp = (u & 1) ? h0 : h1;   // valid for u >= 1

        float sumE[4], sumW[4];
        if (wv < NCW) {
            if (fastR) {
                floatx4 aE = {0.f, 0.f, 0.f, 0.f}, aWc = {0.f, 0.f, 0.f, 0.f};
                if (u == 0) {
                    // plain cached float4 loads from states (pure input)
                    const float* vrow = states + (size_t)arow * cN + kbase;
#pragma unroll
                    for (int kk = 0; kk < 16; ++kk) {
                        const float4 va = *(const float4*)(vrow + kk * 32);
                        const float4 vb = *(const float4*)(vrow + kk * 32 + 4);
                        half8 a8;
                        a8[0] = (_Float16)clamp01(va.x);
                        a8[1] = (_Float16)clamp01(va.y);
                        a8[2] = (_Float16)clamp01(va.z);
                        a8[3] = (_Float16)clamp01(va.w);
                        a8[4] = (_Float16)clamp01(vb.x);
                        a8[5] = (_Float16)clamp01(vb.y);
                        a8[6] = (_Float16)clamp01(vb.z);
                        a8[7] = (_Float16)clamp01(vb.w);
                        aE  = __builtin_amdgcn_mfma_f32_16x16x32_f16(a8, hfr[kk * 64 + lane], aE,  0, 0, 0);
                        aWc = __builtin_amdgcn_mfma_f32_16x16x32_f16(a8, hfr[1024 + kk * 64 + lane], aWc, 0, 0, 0);
                    }
                } else {
                    // A-gather: 16 pipelined 16B gated-f16 loads, ONE waitcnt.
                    floatx4 raw[16];
                    const _Float16* hrow = hRp + (size_t)arow * cN + kbase;
#pragma unroll
                    for (int kk = 0; kk < 16; ++kk)
                        asm volatile("global_load_dwordx4 %0, %1, off offset:%2 sc0 sc1"
                                     : "=v"(raw[kk]) : "v"(hrow), "n"(kk * 64) : "memory");
                    asm volatile("s_waitcnt vmcnt(0)" ::: "memory");
                    __builtin_amdgcn_sched_barrier(0);   // rule #18
#pragma unroll
                    for (int kk = 0; kk < 16; ++kk) {
                        const half8 a8 = __builtin_bit_cast(half8, raw[kk]);
                        aE  = __builtin_amdgcn_mfma_f32_16x16x32_f16(a8, hfr[kk * 64 + lane], aE,  0, 0, 0);
                        aWc = __builtin_amdgcn_mfma_f32_16x16x32_f16(a8, hfr[1024 + kk * 64 + lane], aWc, 0, 0, 0);
                    }
                }
#pragma unroll
                for (int r = 0; r < 4; ++r) { sumE[r] = aE[r]; sumW[r] = aWc[r]; }
            } else {
                // general recurrent path (slow, correct): reads raw f32 v
                float r4[4] = {0,0,0,0}, w4[4] = {0,0,0,0};
                for (int i = 0; i < cN; ++i) {
                    size_t o = (size_t)i * cN + bj;
                    float mk = mask[o];
                    float sg = sigma[o];
                    float a  = 0.5f / sg;
                    float c  = fmaf(-mu[o], a, 0.5f);
                    float ee = erev[o] * mk, ww = wgt[o] * mk;
#pragma unroll
                    for (int r = 0; r < 4; ++r) {
                        float vi = __hip_atomic_load(&vRp[(size_t)(cb0 + r) * cN + i],
                                                     __ATOMIC_RELAXED, __HIP_MEMORY_SCOPE_AGENT);
                        float g = clamp01(fmaf(vi, a, c));
                        r4[r] = fmaf(g, ee, r4[r]);
                        w4[r] = fmaf(g, ww, w4[r]);
                    }
                }
#pragma unroll
                for (int r = 0; r < 4; ++r) { sumE[r] = r4[r]; sumW[r] = w4[r]; }
            }

            // v update for owned cells (all state in registers)
#pragma unroll
            for (int r = 0; r < 4; ++r) {
                float rr   = sumE[r] + srb[r];
                float wsum = sumW[r] + swv[r];
                float k    = 1.0f / (1.0f + wsum);
                float taun = tau_j * k;
                float inv  = 1.0f / (taun + cDELTA);
                float vn   = (taun * inv) * vold[r] + (cDELTA * inv) * k * rr;
                vold[r] = vn;
            }
        }

        if (u < cUNF - 1) {
            // publish v(u+1) (raw f32 for slow readers, gated f16 for fast);
            // generation barrier gen u+1 (1..5). Safety: slot store follows a
            // __syncthreads that drains all prior memory ops (incl. this
            // block's reads of the buffer being recycled).
            if (wv < NCW) {
                float*    vWp = (u & 1) ? v1 : v0;
                _Float16* hWp = (u & 1) ? h1 : h0;
#pragma unroll
                for (int r = 0; r < 4; ++r) {
                    __hip_atomic_store(&vWp[(size_t)(cb0 + r) * cN + bj], vold[r],
                                       __ATOMIC_RELAXED, __HIP_MEMORY_SCOPE_AGENT);
                    _Float16 g = (_Float16)clamp01(vold[r]);
                    unsigned short gs;
                    memcpy(&gs, &g, 2);
                    unsigned int gi = gs;
                    asm volatile("global_store_short %0, %1, off sc0 sc1"
                                 :: "v"(hWp + (size_t)(cb0 + r) * cN + bj), "v"(gi)
                                 : "memory");
                }
            }
            __syncthreads();               // vmcnt(0) drain of the publishes
            if (tid == 0)
                __hip_atomic_store(mySlot, u + 1,
                                   __ATOMIC_RELAXED, __HIP_MEMORY_SCOPE_AGENT);
            if (tid < NCB) {
                const int* sl = slots + tid * SLOT_STRIDE;
                while (__hip_atomic_load(sl, __ATOMIC_RELAXED,
                                         __HIP_MEMORY_SCOPE_AGENT) < u + 1)
                    __builtin_amdgcn_s_sleep(1);
            }
            __syncthreads();
        }
    }

    // ---- epilogue: final v + mapped outputs ----
    if (wv < NCW) {
        float* vout = out + (size_t)cB * cM;
#pragma unroll
        for (int r = 0; r < 4; ++r) {
            int b = cb0 + r;
            vout[(size_t)b * cN + bj] = vold[r];
            if (bj >= cN - cM)
                out[(size_t)b * cM + (bj - (cN - cM))] = fmaf(vold[r], ow, ob);
        }
    }
}

extern "C" void kernel_launch(void* const* d_in, const int* in_sizes, int n_in,
                              void* d_out, int out_size, void* d_ws, size_t ws_size,
                              hipStream_t stream)
{
    const float* inputs = (const float*)d_in[0];
    const float* states = (const float*)d_in[1];
    const float* tau    = (const float*)d_in[2];
    const float* bias   = (const float*)d_in[3];
    const float* erev   = (const float*)d_in[4];
    const float* wgt    = (const float*)d_in[5];
    const float* sigma  = (const float*)d_in[6];
    const float* mu     = (const float*)d_in[7];
    const float* serev  = (const float*)d_in[8];
    const float* swgt   = (const float*)d_in[9];
    const float* ssigma = (const float*)d_in[10];
    const float* smu    = (const float*)d_in[11];
    const float* mask   = (const float*)d_in[12];
    const float* smask  = (const float*)d_in[13];
    const float* inw    = (const float*)d_in[14];
    const float* inb    = (const float*)d_in[15];
    const float* outw   = (const float*)d_in[16];
    const float* outb   = (const float*)d_in[17];
    float* out = (float*)d_out;
    float* ws  = (float*)d_ws;

    // Single dispatch: 256 blocks x 1024 threads, exactly 1 block/CU
    // (16 waves <= 32, 64KB LDS <= 160KB, VGPR <= 128 via launch_bounds)
    // -> all blocks co-resident; internal spin barriers cannot deadlock.
    // All generation slots start from harness poison (negative as int).
    k_fused<<<NBLK, NT, 0, stream>>>(inputs, states, tau, bias, erev, wgt,
                                     sigma, mu, serev, swgt, ssigma, smu,
                                     mask, smask, inw, inb, outw, outb,
                                     out, ws);
}

// Round 7
// 131.049 us; speedup vs baseline: 4.6771x; 1.0022x over previous
//
#include <hip/hip_runtime.h>
#include <string.h>

// Problem constants
constexpr int cB = 64, cS = 512, cN = 512, cM = 128, cUNF = 6;
constexpr float cDELTA = 0.016666666666666666f;  // DT/UNFOLDS = 0.1/6

// r22: r21 with cheaper unfold barriers.
//   r21 post-mortem: k_fused < 41.8us (below fill in top-5), dur 131.3.
//   With the gather full-machine (~5-8us), the remaining fat is the 5
//   generation barriers: publish-drain -> syncthreads(16 waves) -> slot
//   store -> tid<32 poll -> SECOND syncthreads (~3-4us each).
//   Changes:
//   - Per-wave self-poll: each compute wave's lanes 0..31 poll all 32 slots
//     via __all and proceed independently; the post-poll __syncthreads is
//     removed (1 block barrier per unfold, idle waves decoupled on release).
//     Safety unchanged: slot >= g still implies all blocks' gen-(g-1) reads
//     completed before anyone overwrites that ping-pong buffer.
//   - Conditional f32 publish: anySlowR = OR(badf[0..31]) computed once
//     after the done-barrier (folded into existing syncs); the 4 f32 sc1
//     stores/lane/unfold are skipped when no slow-path reader exists.
constexpr int JT   = 16;            // j-columns per compute block
constexpr int NCB  = cN / JT;       // 32 compute blocks
constexpr int NBLK = 256;           // total blocks (1 per CU)
constexpr int NT   = 1024;          // 16 waves
constexpr int NCW  = 4;             // compute waves (wave mt owns batch tile)
constexpr int SLOT_STRIDE = 16;     // ints; 64 B slot spacing

// ws layout (float offsets)
constexpr size_t OFF_V0   = 0;                            // [B][N] f32 ping
constexpr size_t OFF_V1   = (size_t)cB * cN;              // [B][N] f32 pong
constexpr size_t OFF_H0   = OFF_V1 + (size_t)cB * cN;     // [B][N] f16 ping
constexpr size_t OFF_H1   = OFF_H0 + (size_t)cB * cN / 2; // [B][N] f16 pong
constexpr size_t OFF_SLOT = OFF_H1 + (size_t)cB * cN / 2; // 32 slots x 16 ints = 512
constexpr size_t OFF_DONE = OFF_SLOT + 512;               // 256 slots x 16 ints = 4096
constexpr size_t OFF_BAD  = OFF_DONE + 4096;              // 64 ints
constexpr size_t OFF_PK   = 131072;                       // packed table, 2 MB
static_assert(OFF_BAD + 64 <= OFF_PK, "control region must not alias packed table");
// packed table: per jt a 64KB LDS image: [mat4][1024 frags][16B], mat4 =
// {recE, recW, sensE, sensW}; frag = kk*64 + lg*16 + lr; elem t at byte 2t.

typedef _Float16 half8 __attribute__((ext_vector_type(8)));
typedef float    floatx4 __attribute__((ext_vector_type(4)));

__device__ __forceinline__ float clamp01(float x) {
    return __builtin_amdgcn_fmed3f(x, 0.0f, 1.0f);
}

__device__ __forceinline__ unsigned pack2h(float lo, float hi) {
    _Float16 l = (_Float16)lo, h = (_Float16)hi;
    unsigned short ls, hs;
    memcpy(&ls, &l, 2); memcpy(&hs, &h, 2);
    return (unsigned)ls | ((unsigned)hs << 16);
}

__global__ __launch_bounds__(NT, 1)
void k_fused(const float* __restrict__ inputs, const float* __restrict__ states,
             const float* __restrict__ tau,    const float* __restrict__ bias,
             const float* __restrict__ erev,   const float* __restrict__ wgt,
             const float* __restrict__ sigma,  const float* __restrict__ mu,
             const float* __restrict__ serev,  const float* __restrict__ swgt,
             const float* __restrict__ ssigma, const float* __restrict__ smu,
             const float* __restrict__ mask,   const float* __restrict__ smask,
             const float* __restrict__ inw,    const float* __restrict__ inb,
             const float* __restrict__ outw,   const float* __restrict__ outb,
             float* __restrict__ out, float* __restrict__ ws)
{
    float* v0 = ws + OFF_V0;
    float* v1 = ws + OFF_V1;
    _Float16* h0 = (_Float16*)(ws + OFF_H0);
    _Float16* h1 = (_Float16*)(ws + OFF_H1);
    int* slots = (int*)(ws + OFF_SLOT);
    int* done  = (int*)(ws + OFF_DONE);
    int* badf  = (int*)(ws + OFF_BAD);
    unsigned* pk = (unsigned*)(ws + OFF_PK);

    const int tid = threadIdx.x, blk = blockIdx.x;

    // ================= phase 1: cooperative gather (all 256 blocks) ========
    {
        const unsigned g = (unsigned)blk * NT + tid;     // [0, 262144)
        const int lr  = g & 15;           // column within j-tile
        const int qp  = (g >> 4) & 3;     // t-pair (t = 2qp, 2qp+1)
        const int lg2 = (g >> 6) & 3;     // k-group
        const int kk2 = (g >> 8) & 15;    // K-step
        const int jt2 = (g >> 12) & 31;   // j-tile
        const int m2  = (g >> 17) & 1;    // 0 = recurrent, 1 = sensory

        const float* E  = m2 ? serev  : erev;
        const float* W  = m2 ? swgt   : wgt;
        const float* SG = m2 ? ssigma : sigma;
        const float* MU = m2 ? smu    : mu;
        const float* MK = m2 ? smask  : mask;

        const int j  = jt2 * JT + lr;
        const int i0 = kk2 * 32 + lg2 * 8 + qp * 2;
        const size_t o0 = (size_t)i0 * cN + j, o1 = o0 + cN;
        const float e0 = E[o0],  e1 = E[o1];
        const float w0 = W[o0],  w1 = W[o1];
        const float m0 = MK[o0], m1 = MK[o1];
        const float s0 = SG[o0], s1 = SG[o1];
        const float u0 = MU[o0], u1 = MU[o1];
        const bool bad = (m0 != 0.f && (s0 != 0.5f || u0 != 0.5f)) ||
                         (m1 != 0.f && (s1 != 0.5f || u1 != 0.5f));

        const unsigned ed = pack2h(e0 * m0, e1 * m1);
        const unsigned wd = pack2h(w0 * m0, w1 * m1);
        const int frag = kk2 * 64 + lg2 * 16 + lr;
        unsigned* base = pk + (size_t)jt2 * 16384 + (m2 * 2) * 4096 + frag * 4 + qp;
        __hip_atomic_store(base,        ed, __ATOMIC_RELAXED, __HIP_MEMORY_SCOPE_AGENT);
        __hip_atomic_store(base + 4096, wd, __ATOMIC_RELAXED, __HIP_MEMORY_SCOPE_AGENT);
        if (bad)
            __hip_atomic_store(&badf[m2 * 32 + jt2], 1,
                               __ATOMIC_RELAXED, __HIP_MEMORY_SCOPE_AGENT);
    }
    __syncthreads();                       // vmcnt(0) drain of all gather stores
    if (tid == 0)
        __hip_atomic_store(&done[blk * SLOT_STRIDE], 1,
                           __ATOMIC_RELAXED, __HIP_MEMORY_SCOPE_AGENT);
    if (blk >= NCB) return;                // helper blocks done

    // ================= phase 2: compute blocks 0..31 =======================
    const int j0   = blk * JT;
    const int lane = tid & 63;
    const int wv   = tid >> 6;          // wave id 0..15; compute waves: wv < 4
    const int mt   = wv;                // M-tile (batch group of 16)
    const int lr   = lane & 15;
    const int lg   = lane >> 4;
    const int bj   = j0 + lr;           // this lane's output column j (B/C)
    const int arow = mt * 16 + lr;      // A-fragment row (batch)
    const int kbase = lg * 8;
    const int cb0  = mt * 16 + lg * 4;  // first owned batch row (C mapping)

    int* mySlot = slots + blk * SLOT_STRIDE;

    __shared__ _Float16 Hlds[32768];    // 64 KB fragment table (LDS image)
    __shared__ int sAny;                // anySlowR flag
    const half8* hfr = (const half8*)Hlds;

    if (tid == 0) sAny = 0;

    // ---- per-lane owned cells (compute waves) ----
    float vold[4] = {0.f, 0.f, 0.f, 0.f};
    float tau_j = 0.f, bias_j = 0.f, ow = 0.f, ob = 0.f;
    if (wv < NCW) {
#pragma unroll
        for (int r = 0; r < 4; ++r)
            vold[r] = states[(size_t)(cb0 + r) * cN + bj];
        tau_j  = tau[bj];
        bias_j = bias[bj];
        if (bj >= cN - cM) { ow = outw[bj - (cN - cM)]; ob = outb[bj - (cN - cM)]; }
    }

    // ---- wait for all 256 gather-done flags (parallel polls) ----
    if (tid < NBLK) {
        const int* sl = done + tid * SLOT_STRIDE;
        while (__hip_atomic_load(sl, __ATOMIC_RELAXED, __HIP_MEMORY_SCOPE_AGENT) < 1)
            __builtin_amdgcn_s_sleep(1);
    }
    __syncthreads();                       // done flags + sAny init visible

    const bool fastR = (__hip_atomic_load(&badf[blk], __ATOMIC_RELAXED,
                                          __HIP_MEMORY_SCOPE_AGENT) != 1);
    const bool fastS = (__hip_atomic_load(&badf[32 + blk], __ATOMIC_RELAXED,
                                          __HIP_MEMORY_SCOPE_AGENT) != 1);
    if (tid < 32 &&
        __hip_atomic_load(&badf[tid], __ATOMIC_RELAXED,
                          __HIP_MEMORY_SCOPE_AGENT) == 1)
        sAny = 1;                          // benign LDS race (same value)

    // ---- LDS fill: 64KB slice, 4 x 16B burst loads (bypass stale L1/L2) ----
    {
        const uint4* src = (const uint4*)pk + (size_t)blk * 4096;
        floatx4 tmp[4];
#pragma unroll
        for (int r = 0; r < 4; ++r)
            asm volatile("global_load_dwordx4 %0, %1, off sc0 sc1"
                         : "=v"(tmp[r]) : "v"(src + r * 1024 + tid) : "memory");
        asm volatile("s_waitcnt vmcnt(0)" ::: "memory");
        __builtin_amdgcn_sched_barrier(0);   // rule #18
#pragma unroll
        for (int r = 0; r < 4; ++r)
            ((uint4*)Hlds)[r * 1024 + tid] = __builtin_bit_cast(uint4, tmp[r]);
    }
    __syncthreads();                       // table + sAny ready
    const bool pubF32 = (sAny == 1);       // any slow recurrent reader exists?

    // ---- sensory reduction -> srb (s_rev + bias), swv (s_w) ----
    float srb[4] = {0.f, 0.f, 0.f, 0.f}, swv[4] = {0.f, 0.f, 0.f, 0.f};
    if (wv < NCW) {
        if (fastS) {
            floatx4 aR = {0.f, 0.f, 0.f, 0.f}, aW = {0.f, 0.f, 0.f, 0.f};
#pragma unroll
            for (int kk = 0; kk < 16; ++kk) {
                const int off = kk * 32 + kbase;
                const float4 xa = *(const float4*)(inputs + (size_t)arow * cS + off);
                const float4 xb = *(const float4*)(inputs + (size_t)arow * cS + off + 4);
                const float4 wa = *(const float4*)(inw + off);
                const float4 wb = *(const float4*)(inw + off + 4);
                const float4 ba = *(const float4*)(inb + off);
                const float4 bb = *(const float4*)(inb + off + 4);
                half8 ax;
                ax[0] = (_Float16)clamp01(fmaf(xa.x, wa.x, ba.x));
                ax[1] = (_Float16)clamp01(fmaf(xa.y, wa.y, ba.y));
                ax[2] = (_Float16)clamp01(fmaf(xa.z, wa.z, ba.z));
                ax[3] = (_Float16)clamp01(fmaf(xa.w, wa.w, ba.w));
                ax[4] = (_Float16)clamp01(fmaf(xb.x, wb.x, bb.x));
                ax[5] = (_Float16)clamp01(fmaf(xb.y, wb.y, bb.y));
                ax[6] = (_Float16)clamp01(fmaf(xb.z, wb.z, bb.z));
                ax[7] = (_Float16)clamp01(fmaf(xb.w, wb.w, bb.w));
                aR = __builtin_amdgcn_mfma_f32_16x16x32_f16(ax, hfr[2048 + kk * 64 + lane], aR, 0, 0, 0);
                aW = __builtin_amdgcn_mfma_f32_16x16x32_f16(ax, hfr[3072 + kk * 64 + lane], aW, 0, 0, 0);
            }
#pragma unroll
            for (int r = 0; r < 4; ++r) { srb[r] = aR[r] + bias_j; swv[r] = aW[r]; }
        } else {
            // general sensory path (slow, correct, unexercised by the bench)
            float sr4[4] = {0,0,0,0}, sw4[4] = {0,0,0,0};
            for (int s = 0; s < cS; ++s) {
                size_t o = (size_t)s * cN + bj;
                float mk = smask[o];
                float sg = ssigma[o];
                float a  = 0.5f / sg;
                float c  = fmaf(-smu[o], a, 0.5f);
                float ee = serev[o] * mk, ww = swgt[o] * mk;
                float iw = inw[s], ib = inb[s];
#pragma unroll
                for (int r = 0; r < 4; ++r) {
                    float x = fmaf(inputs[(size_t)(cb0 + r) * cS + s], iw, ib);
                    float g = clamp01(fmaf(x, a, c));
                    sr4[r] = fmaf(g, ee, sr4[r]);
                    sw4[r] = fmaf(g, ww, sw4[r]);
                }
            }
#pragma unroll
            for (int r = 0; r < 4; ++r) { srb[r] = sr4[r] + bias_j; swv[r] = sw4[r]; }
        }
    }

    // ---- 6 unfolds; unfold 0 reads `states` directly ----
    for (int u = 0; u < cUNF; ++u) {
        const float*    vRp = (u == 0) ? states : ((u & 1) ? v0 : v1);
        const _Float16* hRp = (u & 1) ? h0 : h1;   // valid for u >= 1

        float sumE[4], sumW[4];
        if (wv < NCW) {
            if (fastR) {
                floatx4 aE = {0.f, 0.f, 0.f, 0.f}, aWc = {0.f, 0.f, 0.f, 0.f};
                if (u == 0) {
                    // plain cached float4 loads from states (pure input)
                    const float* vrow = states + (size_t)arow * cN + kbase;
#pragma unroll
                    for (int kk = 0; kk < 16; ++kk) {
                        const float4 va = *(const float4*)(vrow + kk * 32);
                        const float4 vb = *(const float4*)(vrow + kk * 32 + 4);
                        half8 a8;
                        a8[0] = (_Float16)clamp01(va.x);
                        a8[1] = (_Float16)clamp01(va.y);
                        a8[2] = (_Float16)clamp01(va.z);
                        a8[3] = (_Float16)clamp01(va.w);
                        a8[4] = (_Float16)clamp01(vb.x);
                        a8[5] = (_Float16)clamp01(vb.y);
                        a8[6] = (_Float16)clamp01(vb.z);
                        a8[7] = (_Float16)clamp01(vb.w);
                        aE  = __builtin_amdgcn_mfma_f32_16x16x32_f16(a8, hfr[kk * 64 + lane], aE,  0, 0, 0);
                        aWc = __builtin_amdgcn_mfma_f32_16x16x32_f16(a8, hfr[1024 + kk * 64 + lane], aWc, 0, 0, 0);
                    }
                } else {
                    // A-gather: 16 pipelined 16B gated-f16 loads, ONE waitcnt.
                    floatx4 raw[16];
                    const _Float16* hrow = hRp + (size_t)arow * cN + kbase;
#pragma unroll
                    for (int kk = 0; kk < 16; ++kk)
                        asm volatile("global_load_dwordx4 %0, %1, off offset:%2 sc0 sc1"
                                     : "=v"(raw[kk]) : "v"(hrow), "n"(kk * 64) : "memory");
                    asm volatile("s_waitcnt vmcnt(0)" ::: "memory");
                    __builtin_amdgcn_sched_barrier(0);   // rule #18
#pragma unroll
                    for (int kk = 0; kk < 16; ++kk) {
                        const half8 a8 = __builtin_bit_cast(half8, raw[kk]);
                        aE  = __builtin_amdgcn_mfma_f32_16x16x32_f16(a8, hfr[kk * 64 + lane], aE,  0, 0, 0);
                        aWc = __builtin_amdgcn_mfma_f32_16x16x32_f16(a8, hfr[1024 + kk * 64 + lane], aWc, 0, 0, 0);
                    }
                }
#pragma unroll
                for (int r = 0; r < 4; ++r) { sumE[r] = aE[r]; sumW[r] = aWc[r]; }
            } else {
                // general recurrent path (slow, correct): reads raw f32 v
                float r4[4] = {0,0,0,0}, w4[4] = {0,0,0,0};
                for (int i = 0; i < cN; ++i) {
                    size_t o = (size_t)i * cN + bj;
                    float mk = mask[o];
                    float sg = sigma[o];
                    float a  = 0.5f / sg;
                    float c  = fmaf(-mu[o], a, 0.5f);
                    float ee = erev[o] * mk, ww = wgt[o] * mk;
#pragma unroll
                    for (int r = 0; r < 4; ++r) {
                        float vi = __hip_atomic_load(&vRp[(size_t)(cb0 + r) * cN + i],
                                                     __ATOMIC_RELAXED, __HIP_MEMORY_SCOPE_AGENT);
                        float g = clamp01(fmaf(vi, a, c));
                        r4[r] = fmaf(g, ee, r4[r]);
                        w4[r] = fmaf(g, ww, w4[r]);
                    }
                }
#pragma unroll
                for (int r = 0; r < 4; ++r) { sumE[r] = r4[r]; sumW[r] = w4[r]; }
            }

            // v update for owned cells (all state in registers)
#pragma unroll
            for (int r = 0; r < 4; ++r) {
                float rr   = sumE[r] + srb[r];
                float wsum = sumW[r] + swv[r];
                float k    = 1.0f / (1.0f + wsum);
                float taun = tau_j * k;
                float inv  = 1.0f / (taun + cDELTA);
                float vn   = (taun * inv) * vold[r] + (cDELTA * inv) * k * rr;
                vold[r] = vn;
            }
        }

        if (u < cUNF - 1) {
            // publish v(u+1): gated f16 always; raw f32 only if a slow
            // recurrent reader exists anywhere (pubF32).
            if (wv < NCW) {
                float*    vWp = (u & 1) ? v1 : v0;
                _Float16* hWp = (u & 1) ? h1 : h0;
#pragma unroll
                for (int r = 0; r < 4; ++r) {
                    if (pubF32)
                        __hip_atomic_store(&vWp[(size_t)(cb0 + r) * cN + bj], vold[r],
                                           __ATOMIC_RELAXED, __HIP_MEMORY_SCOPE_AGENT);
                    _Float16 g = (_Float16)clamp01(vold[r]);
                    unsigned short gs;
                    memcpy(&gs, &g, 2);
                    unsigned int gi = gs;
                    asm volatile("global_store_short %0, %1, off sc0 sc1"
                                 :: "v"(hWp + (size_t)(cb0 + r) * cN + bj), "v"(gi)
                                 : "memory");
                }
            }
            __syncthreads();               // vmcnt(0) drain of the publishes
            if (tid == 0)
                __hip_atomic_store(mySlot, u + 1,
                                   __ATOMIC_RELAXED, __HIP_MEMORY_SCOPE_AGENT);
            // per-wave self-poll: lanes 0..31 of each compute wave poll the
            // 32 slots; wave proceeds as soon as all are >= u+1. No second
            // __syncthreads: slot >= g already implies every block finished
            // its gen-(g-1) reads, so overwriting that buffer is safe.
            if (wv < NCW) {
                const int* sl = slots + (lane & 31) * SLOT_STRIDE;
                bool ok;
                do {
                    int v = (lane < 32)
                        ? __hip_atomic_load(sl, __ATOMIC_RELAXED, __HIP_MEMORY_SCOPE_AGENT)
                        : 0x7fffffff;
                    ok = __all((int)(v >= u + 1));
                } while (!ok);
            }
        }
    }

    // ---- epilogue: final v + mapped outputs ----
    if (wv < NCW) {
        float* vout = out + (size_t)cB * cM;
#pragma unroll
        for (int r = 0; r < 4; ++r) {
            int b = cb0 + r;
            vout[(size_t)b * cN + bj] = vold[r];
            if (bj >= cN - cM)
                out[(size_t)b * cM + (bj - (cN - cM))] = fmaf(vold[r], ow, ob);
        }
    }
}

extern "C" void kernel_launch(void* const* d_in, const int* in_sizes, int n_in,
                              void* d_out, int out_size, void* d_ws, size_t ws_size,
                              hipStream_t stream)
{
    const float* inputs = (const float*)d_in[0];
    const float* states = (const float*)d_in[1];
    const float* tau    = (const float*)d_in[2];
    const float* bias   = (const float*)d_in[3];
    const float* erev   = (const float*)d_in[4];
    const float* wgt    = (const float*)d_in[5];
    const float* sigma  = (const float*)d_in[6];
    const float* mu     = (const float*)d_in[7];
    const float* serev  = (const float*)d_in[8];
    const float* swgt   = (const float*)d_in[9];
    const float* ssigma = (const float*)d_in[10];
    const float* smu    = (const float*)d_in[11];
    const float* mask   = (const float*)d_in[12];
    const float* smask  = (const float*)d_in[13];
    const float* inw    = (const float*)d_in[14];
    const float* inb    = (const float*)d_in[15];
    const float* outw   = (const float*)d_in[16];
    const float* outb   = (const float*)d_in[17];
    float* out = (float*)d_out;
    float* ws  = (float*)d_ws;

    // Single dispatch: 256 blocks x 1024 threads, exactly 1 block/CU
    // (16 waves <= 32, 64KB LDS <= 160KB, VGPR <= 128 via launch_bounds)
    // -> all blocks co-resident; internal spin barriers cannot deadlock.
    // All generation slots start from harness poison (negative as int).
    k_fused<<<NBLK, NT, 0, stream>>>(inputs, states, tau, bias, erev, wgt,
                                     sigma, mu, serev, swgt, ssigma, smu,
                                     mask, smask, inw, inb, outw, outb,
                                     out, ws);
}

// Round 9
// 125.186 us; speedup vs baseline: 4.8961x; 1.0468x over previous
//
#include <hip/hip_runtime.h>
#include <string.h>

// Problem constants
constexpr int cB = 64, cS = 512, cN = 512, cM = 128, cUNF = 6;
constexpr float cDELTA = 0.016666666666666666f;  // DT/UNFOLDS = 0.1/6

// r24: r23 with the helper-pack OOB bug fixed.
//   r23 post-mortem: container failed twice = GPU fault. The hx/hs0 helper
//   packing mapped 32768 dwords to each 16384-dword region: b = p2>>9 ran to
//   127 (B=64) -> OOB reads 128KB past inputs/states (page fault) and OOB
//   stores over OFF_SLOT/OFF_DONE/OFF_BAD. Fix: q<16384 -> hx,
//   16384<=q<32768 -> hs0, rest idle; static_asserts on region sizes.
//   Design otherwise unchanged from r23 (unmeasured):
//   - Phase 1 (all 256 blocks) packs the 2MB f16 fragment table; helper
//     blocks 192..223 also pack hx = f16 gated input map and hs0 = f16
//     gated initial state (bit-identical to the per-block computation they
//     replace).
//   - Plain (L2-cached) loads for phase-1-produced data (table, hx, hs0):
//     each address written exactly once (sc1) before the done handshake;
//     reader-XCD L2 lines are absent (kernel-launch invalidate) or
//     fresh-from-writer => no staleness; 4 compute blocks/XCD share pulls.
//   - Ping-pong h0/h1 keep sc0 sc1 (addresses reused across generations).
//   - Per-wave self-poll with s_sleep backoff; conditional f32 publish.
constexpr int JT   = 16;            // j-columns per compute block
constexpr int NCB  = cN / JT;       // 32 compute blocks
constexpr int NBLK = 256;           // total blocks (1 per CU)
constexpr int NT   = 1024;          // 16 waves
constexpr int NCW  = 4;             // compute waves (wave mt owns batch tile)
constexpr int SLOT_STRIDE = 16;     // ints; 64 B slot spacing

// ws layout (float offsets)
constexpr size_t OFF_V0   = 0;                 // [B][N] f32 ping (slow path)
constexpr size_t OFF_V1   = 32768;             // [B][N] f32 pong (slow path)
constexpr size_t OFF_H0   = 65536;             // [B][N] f16 ping
constexpr size_t OFF_H1   = 81920;             // [B][N] f16 pong
constexpr size_t OFF_HX   = 98304;             // [B][S] f16 gated input map
constexpr size_t OFF_HS0  = 114688;            // [B][N] f16 gated states
constexpr size_t OFF_SLOT = 131072;            // 32 slots x 16 ints
constexpr size_t OFF_DONE = OFF_SLOT + 512;    // 256 slots x 16 ints
constexpr size_t OFF_BAD  = OFF_DONE + 4096;   // 64 ints
constexpr size_t OFF_PK   = 262144;            // packed table, 2 MB
static_assert(OFF_BAD + 64 <= OFF_PK, "control region must not alias packed table");
static_assert(OFF_H0  + (size_t)cB * cN / 2 <= OFF_H1,   "h0 fits");
static_assert(OFF_H1  + (size_t)cB * cN / 2 <= OFF_HX,   "h1 fits");
static_assert(OFF_HX  + (size_t)cB * cS / 2 <= OFF_HS0,  "hx fits");
static_assert(OFF_HS0 + (size_t)cB * cN / 2 <= OFF_SLOT, "hs0 fits");
// hx/hs0 dword counts (one dword = 2 f16 elements)
constexpr unsigned HX_DW  = (unsigned)cB * cS / 2;  // 16384
constexpr unsigned HS0_DW = (unsigned)cB * cN / 2;  // 16384
// packed table: per jt a 64KB LDS image: [mat4][1024 frags][16B], mat4 =
// {recE, recW, sensE, sensW}; frag = kk*64 + lg*16 + lr; elem t at byte 2t.

typedef _Float16 half8 __attribute__((ext_vector_type(8)));
typedef float    floatx4 __attribute__((ext_vector_type(4)));

__device__ __forceinline__ float clamp01(float x) {
    return __builtin_amdgcn_fmed3f(x, 0.0f, 1.0f);
}

__device__ __forceinline__ unsigned pack2h(float lo, float hi) {
    _Float16 l = (_Float16)lo, h = (_Float16)hi;
    unsigned short ls, hs;
    memcpy(&ls, &l, 2); memcpy(&hs, &h, 2);
    return (unsigned)ls | ((unsigned)hs << 16);
}

__global__ __launch_bounds__(NT, 1)
void k_fused(const float* __restrict__ inputs, const float* __restrict__ states,
             const float* __restrict__ tau,    const float* __restrict__ bias,
             const float* __restrict__ erev,   const float* __restrict__ wgt,
             const float* __restrict__ sigma,  const float* __restrict__ mu,
             const float* __restrict__ serev,  const float* __restrict__ swgt,
             const float* __restrict__ ssigma, const float* __restrict__ smu,
             const float* __restrict__ mask,   const float* __restrict__ smask,
             const float* __restrict__ inw,    const float* __restrict__ inb,
             const float* __restrict__ outw,   const float* __restrict__ outb,
             float* __restrict__ out, float* __restrict__ ws)
{
    float* v0 = ws + OFF_V0;
    float* v1 = ws + OFF_V1;
    _Float16* h0 = (_Float16*)(ws + OFF_H0);
    _Float16* h1 = (_Float16*)(ws + OFF_H1);
    _Float16* hx  = (_Float16*)(ws + OFF_HX);
    _Float16* hs0 = (_Float16*)(ws + OFF_HS0);
    int* slots = (int*)(ws + OFF_SLOT);
    int* done  = (int*)(ws + OFF_DONE);
    int* badf  = (int*)(ws + OFF_BAD);
    unsigned* pk = (unsigned*)(ws + OFF_PK);

    const int tid = threadIdx.x, blk = blockIdx.x;

    // ================= phase 1: cooperative gather (all 256 blocks) ========
    {
        const unsigned g = (unsigned)blk * NT + tid;     // [0, 262144)
        const int lr  = g & 15;           // column within j-tile
        const int qp  = (g >> 4) & 3;     // t-pair (t = 2qp, 2qp+1)
        const int lg2 = (g >> 6) & 3;     // k-group
        const int kk2 = (g >> 8) & 15;    // K-step
        const int jt2 = (g >> 12) & 31;   // j-tile
        const int m2  = (g >> 17) & 1;    // 0 = recurrent, 1 = sensory

        const float* E  = m2 ? serev  : erev;
        const float* W  = m2 ? swgt   : wgt;
        const float* SG = m2 ? ssigma : sigma;
        const float* MU = m2 ? smu    : mu;
        const float* MK = m2 ? smask  : mask;

        const int j  = jt2 * JT + lr;
        const int i0 = kk2 * 32 + lg2 * 8 + qp * 2;
        const size_t o0 = (size_t)i0 * cN + j, o1 = o0 + cN;
        const float e0 = E[o0],  e1 = E[o1];
        const float w0 = W[o0],  w1 = W[o1];
        const float m0 = MK[o0], m1 = MK[o1];
        const float s0 = SG[o0], s1 = SG[o1];
        const float u0 = MU[o0], u1 = MU[o1];
        const bool bad = (m0 != 0.f && (s0 != 0.5f || u0 != 0.5f)) ||
                         (m1 != 0.f && (s1 != 0.5f || u1 != 0.5f));

        const unsigned ed = pack2h(e0 * m0, e1 * m1);
        const unsigned wd = pack2h(w0 * m0, w1 * m1);
        const int frag = kk2 * 64 + lg2 * 16 + lr;
        unsigned* base = pk + (size_t)jt2 * 16384 + (m2 * 2) * 4096 + frag * 4 + qp;
        __hip_atomic_store(base,        ed, __ATOMIC_RELAXED, __HIP_MEMORY_SCOPE_AGENT);
        __hip_atomic_store(base + 4096, wd, __ATOMIC_RELAXED, __HIP_MEMORY_SCOPE_AGENT);
        if (bad)
            __hip_atomic_store(&badf[m2 * 32 + jt2], 1,
                               __ATOMIC_RELAXED, __HIP_MEMORY_SCOPE_AGENT);

        // helper blocks 192..223 also pack the A-matrices (hx, hs0):
        // one f16x2 dword per thread, coalesced sc1 stores. Bounds: q <
        // HX_DW -> hx (b = 2q>>9 in [0,64)), next HS0_DW -> hs0, rest idle.
        if (g >= 196608) {
            const unsigned q = g - 196608;           // [0, 65536)
            if (q < HX_DW) {
                const unsigned p2 = q * 2;           // element index [0, 32768)
                const int b = p2 >> 9, s = p2 & (cS - 1);
                const size_t o = (size_t)b * cS + s;
                float xa = clamp01(fmaf(inputs[o],     inw[s],     inb[s]));
                float xb = clamp01(fmaf(inputs[o + 1], inw[s + 1], inb[s + 1]));
                __hip_atomic_store((unsigned*)hx + q, pack2h(xa, xb),
                                   __ATOMIC_RELAXED, __HIP_MEMORY_SCOPE_AGENT);
            } else if (q < HX_DW + HS0_DW) {
                const unsigned qq = q - HX_DW;       // [0, 16384)
                const unsigned p2 = qq * 2;          // element index [0, 32768)
                const int b = p2 >> 9, n = p2 & (cN - 1);
                const size_t o = (size_t)b * cN + n;
                float va = clamp01(states[o]);
                float vb = clamp01(states[o + 1]);
                __hip_atomic_store((unsigned*)hs0 + qq, pack2h(va, vb),
                                   __ATOMIC_RELAXED, __HIP_MEMORY_SCOPE_AGENT);
            }
        }
    }
    __syncthreads();                       // vmcnt(0) drain of all gather stores
    if (tid == 0)
        __hip_atomic_store(&done[blk * SLOT_STRIDE], 1,
                           __ATOMIC_RELAXED, __HIP_MEMORY_SCOPE_AGENT);
    if (blk >= NCB) return;                // helper blocks done

    // ================= phase 2: compute blocks 0..31 =======================
    const int j0   = blk * JT;
    const int lane = tid & 63;
    const int wv   = tid >> 6;          // wave id 0..15; compute waves: wv < 4
    const int mt   = wv;                // M-tile (batch group of 16)
    const int lr   = lane & 15;
    const int lg   = lane >> 4;
    const int bj   = j0 + lr;           // this lane's output column j (B/C)
    const int arow = mt * 16 + lr;      // A-fragment row (batch)
    const int kbase = lg * 8;
    const int cb0  = mt * 16 + lg * 4;  // first owned batch row (C mapping)

    int* mySlot = slots + blk * SLOT_STRIDE;

    __shared__ _Float16 Hlds[32768];    // 64 KB fragment table (LDS image)
    __shared__ int sAny;                // anySlowR flag
    const half8* hfr = (const half8*)Hlds;

    if (tid == 0) sAny = 0;

    // ---- per-lane owned cells (compute waves) ----
    float vold[4] = {0.f, 0.f, 0.f, 0.f};
    float tau_j = 0.f, bias_j = 0.f, ow = 0.f, ob = 0.f;
    if (wv < NCW) {
#pragma unroll
        for (int r = 0; r < 4; ++r)
            vold[r] = states[(size_t)(cb0 + r) * cN + bj];
        tau_j  = tau[bj];
        bias_j = bias[bj];
        if (bj >= cN - cM) { ow = outw[bj - (cN - cM)]; ob = outb[bj - (cN - cM)]; }
    }

    // ---- wait for all 256 gather-done flags (parallel polls) ----
    if (tid < NBLK) {
        const int* sl = done + tid * SLOT_STRIDE;
        while (__hip_atomic_load(sl, __ATOMIC_RELAXED, __HIP_MEMORY_SCOPE_AGENT) < 1)
            __builtin_amdgcn_s_sleep(1);
    }
    __syncthreads();                       // done flags + sAny init visible

    const bool fastR = (__hip_atomic_load(&badf[blk], __ATOMIC_RELAXED,
                                          __HIP_MEMORY_SCOPE_AGENT) != 1);
    const bool fastS = (__hip_atomic_load(&badf[32 + blk], __ATOMIC_RELAXED,
                                          __HIP_MEMORY_SCOPE_AGENT) != 1);
    if (tid < 32 &&
        __hip_atomic_load(&badf[tid], __ATOMIC_RELAXED,
                          __HIP_MEMORY_SCOPE_AGENT) == 1)
        sAny = 1;                          // benign LDS race (same value)

    // ---- LDS fill: 64KB slice, PLAIN cached dwordx4 loads.
    //   Safe: each table address was written exactly once (sc1) before the
    //   done handshake; this XCD's L2 line is absent (kernel-launch
    //   invalidate cleared fill poison) or fresh-from-writer. L2 caching
    //   lets the 4 compute blocks per XCD share the pull. ----
    {
        const uint4* src = (const uint4*)pk + (size_t)blk * 4096;
#pragma unroll
        for (int r = 0; r < 4; ++r)
            ((uint4*)Hlds)[r * 1024 + tid] = src[r * 1024 + tid];
    }
    __syncthreads();                       // table + sAny ready
    const bool pubF32 = (sAny == 1);       // any slow recurrent reader exists?

    // ---- sensory reduction -> srb (s_rev + bias), swv (s_w) ----
    float srb[4] = {0.f, 0.f, 0.f, 0.f}, swv[4] = {0.f, 0.f, 0.f, 0.f};
    if (wv < NCW) {
        if (fastS) {
            // A-gather from pre-packed hx (plain cached loads, L2-shared)
            uint4 raw[16];
            const uint4* xr = (const uint4*)(hx + (size_t)arow * cS);
#pragma unroll
            for (int kk = 0; kk < 16; ++kk)
                raw[kk] = xr[kk * 4 + lg];
            floatx4 aR = {0.f, 0.f, 0.f, 0.f}, aW = {0.f, 0.f, 0.f, 0.f};
#pragma unroll
            for (int kk = 0; kk < 16; ++kk) {
                const half8 a8 = __builtin_bit_cast(half8, raw[kk]);
                aR = __builtin_amdgcn_mfma_f32_16x16x32_f16(a8, hfr[2048 + kk * 64 + lane], aR, 0, 0, 0);
                aW = __builtin_amdgcn_mfma_f32_16x16x32_f16(a8, hfr[3072 + kk * 64 + lane], aW, 0, 0, 0);
            }
#pragma unroll
            for (int r = 0; r < 4; ++r) { srb[r] = aR[r] + bias_j; swv[r] = aW[r]; }
        } else {
            // general sensory path (slow, correct, unexercised by the bench)
            float sr4[4] = {0,0,0,0}, sw4[4] = {0,0,0,0};
            for (int s = 0; s < cS; ++s) {
                size_t o = (size_t)s * cN + bj;
                float mk = smask[o];
                float sg = ssigma[o];
                float a  = 0.5f / sg;
                float c  = fmaf(-smu[o], a, 0.5f);
                float ee = serev[o] * mk, ww = swgt[o] * mk;
                float iw = inw[s], ib = inb[s];
#pragma unroll
                for (int r = 0; r < 4; ++r) {
                    float x = fmaf(inputs[(size_t)(cb0 + r) * cS + s], iw, ib);
                    float g = clamp01(fmaf(x, a, c));
                    sr4[r] = fmaf(g, ee, sr4[r]);
                    sw4[r] = fmaf(g, ww, sw4[r]);
                }
            }
#pragma unroll
            for (int r = 0; r < 4; ++r) { srb[r] = sr4[r] + bias_j; swv[r] = sw4[r]; }
        }
    }

    // ---- 6 unfolds; unfold 0 reads pre-packed hs0 (plain cached) ----
    for (int u = 0; u < cUNF; ++u) {
        const float*    vRp = (u == 0) ? states : ((u & 1) ? v0 : v1);
        const _Float16* hRp = (u & 1) ? h0 : h1;   // valid for u >= 1

        float sumE[4], sumW[4];
        if (wv < NCW) {
            if (fastR) {
                floatx4 aE = {0.f, 0.f, 0.f, 0.f}, aWc = {0.f, 0.f, 0.f, 0.f};
                if (u == 0) {
                    // A-gather from hs0 (plain cached, L2-shared)
                    uint4 raw[16];
                    const uint4* sr = (const uint4*)(hs0 + (size_t)arow * cN);
#pragma unroll
                    for (int kk = 0; kk < 16; ++kk)
                        raw[kk] = sr[kk * 4 + lg];
#pragma unroll
                    for (int kk = 0; kk < 16; ++kk) {
                        const half8 a8 = __builtin_bit_cast(half8, raw[kk]);
                        aE  = __builtin_amdgcn_mfma_f32_16x16x32_f16(a8, hfr[kk * 64 + lane], aE,  0, 0, 0);
                        aWc = __builtin_amdgcn_mfma_f32_16x16x32_f16(a8, hfr[1024 + kk * 64 + lane], aWc, 0, 0, 0);
                    }
                } else {
                    // A-gather: 16 pipelined 16B gated-f16 loads, ONE waitcnt.
                    // sc0 sc1 (bypass stale L1/L2): h0/h1 addresses are REUSED
                    // across generations, so plain cached loads are unsafe.
                    floatx4 raw[16];
                    const _Float16* hrow = hRp + (size_t)arow * cN + kbase;
#pragma unroll
                    for (int kk = 0; kk < 16; ++kk)
                        asm volatile("global_load_dwordx4 %0, %1, off offset:%2 sc0 sc1"
                                     : "=v"(raw[kk]) : "v"(hrow), "n"(kk * 64) : "memory");
                    asm volatile("s_waitcnt vmcnt(0)" ::: "memory");
                    __builtin_amdgcn_sched_barrier(0);   // rule #18
#pragma unroll
                    for (int kk = 0; kk < 16; ++kk) {
                        const half8 a8 = __builtin_bit_cast(half8, raw[kk]);
                        aE  = __builtin_amdgcn_mfma_f32_16x16x32_f16(a8, hfr[kk * 64 + lane], aE,  0, 0, 0);
                        aWc = __builtin_amdgcn_mfma_f32_16x16x32_f16(a8, hfr[1024 + kk * 64 + lane], aWc, 0, 0, 0);
                    }
                }
#pragma unroll
                for (int r = 0; r < 4; ++r) { sumE[r] = aE[r]; sumW[r] = aWc[r]; }
            } else {
                // general recurrent path (slow, correct): reads raw f32 v
                float r4[4] = {0,0,0,0}, w4[4] = {0,0,0,0};
                for (int i = 0; i < cN; ++i) {
                    size_t o = (size_t)i * cN + bj;
                    float mk = mask[o];
                    float sg = sigma[o];
                    float a  = 0.5f / sg;
                    float c  = fmaf(-mu[o], a, 0.5f);
                    float ee = erev[o] * mk, ww = wgt[o] * mk;
#pragma unroll
                    for (int r = 0; r < 4; ++r) {
                        float vi = __hip_atomic_load(&vRp[(size_t)(cb0 + r) * cN + i],
                                                     __ATOMIC_RELAXED, __HIP_MEMORY_SCOPE_AGENT);
                        float g = clamp01(fmaf(vi, a, c));
                        r4[r] = fmaf(g, ee, r4[r]);
                        w4[r] = fmaf(g, ww, w4[r]);
                    }
                }
#pragma unroll
                for (int r = 0; r < 4; ++r) { sumE[r] = r4[r]; sumW[r] = w4[r]; }
            }

            // v update for owned cells (all state in registers)
#pragma unroll
            for (int r = 0; r < 4; ++r) {
                float rr   = sumE[r] + srb[r];
                float wsum = sumW[r] + swv[r];
                float k    = 1.0f / (1.0f + wsum);
                float taun = tau_j * k;
                float inv  = 1.0f / (taun + cDELTA);
                float vn   = (taun * inv) * vold[r] + (cDELTA * inv) * k * rr;
                vold[r] = vn;
            }
        }

        if (u < cUNF - 1) {
            // publish v(u+1): gated f16 always; raw f32 only if a slow
            // recurrent reader exists anywhere (pubF32).
            if (wv < NCW) {
                float*    vWp = (u & 1) ? v1 : v0;
                _Float16* hWp = (u & 1) ? h1 : h0;
#pragma unroll
                for (int r = 0; r < 4; ++r) {
                    if (pubF32)
                        __hip_atomic_store(&vWp[(size_t)(cb0 + r) * cN + bj], vold[r],
                                           __ATOMIC_RELAXED, __HIP_MEMORY_SCOPE_AGENT);
                    _Float16 g = (_Float16)clamp01(vold[r]);
                    unsigned short gs;
                    memcpy(&gs, &g, 2);
                    unsigned int gi = gs;
                    asm volatile("global_store_short %0, %1, off sc0 sc1"
                                 :: "v"(hWp + (size_t)(cb0 + r) * cN + bj), "v"(gi)
                                 : "memory");
                }
            }
            __syncthreads();               // vmcnt(0) drain of the publishes
            if (tid == 0)
                __hip_atomic_store(mySlot, u + 1,
                                   __ATOMIC_RELAXED, __HIP_MEMORY_SCOPE_AGENT);
            // per-wave self-poll: lanes 0..31 of each compute wave poll the
            // 32 slots; wave proceeds as soon as all are >= u+1. s_sleep
            // backoff (sleepless loop hammered L3: 147us cold spike in r22).
            if (wv < NCW) {
                const int* sl = slots + (lane & 31) * SLOT_STRIDE;
                bool ok;
                do {
                    int v = (lane < 32)
                        ? __hip_atomic_load(sl, __ATOMIC_RELAXED, __HIP_MEMORY_SCOPE_AGENT)
                        : 0x7fffffff;
                    ok = __all((int)(v >= u + 1));
                    if (!ok) __builtin_amdgcn_s_sleep(1);
                } while (!ok);
            }
        }
    }

    // ---- epilogue: final v + mapped outputs ----
    if (wv < NCW) {
        float* vout = out + (size_t)cB * cM;
#pragma unroll
        for (int r = 0; r < 4; ++r) {
            int b = cb0 + r;
            vout[(size_t)b * cN + bj] = vold[r];
            if (bj >= cN - cM)
                out[(size_t)b * cM + (bj - (cN - cM))] = fmaf(vold[r], ow, ob);
        }
    }
}

extern "C" void kernel_launch(void* const* d_in, const int* in_sizes, int n_in,
                              void* d_out, int out_size, void* d_ws, size_t ws_size,
                              hipStream_t stream)
{
    const float* inputs = (const float*)d_in[0];
    const float* states = (const float*)d_in[1];
    const float* tau    = (const float*)d_in[2];
    const float* bias   = (const float*)d_in[3];
    const float* erev   = (const float*)d_in[4];
    const float* wgt    = (const float*)d_in[5];
    const float* sigma  = (const float*)d_in[6];
    const float* mu     = (const float*)d_in[7];
    const float* serev  = (const float*)d_in[8];
    const float* swgt   = (const float*)d_in[9];
    const float* ssigma = (const float*)d_in[10];
    const float* smu    = (const float*)d_in[11];
    const float* mask   = (const float*)d_in[12];
    const float* smask  = (const float*)d_in[13];
    const float* inw    = (const float*)d_in[14];
    const float* inb    = (const float*)d_in[15];
    const float* outw   = (const float*)d_in[16];
    const float* outb   = (const float*)d_in[17];
    float* out = (float*)d_out;
    float* ws  = (float*)d_ws;

    // Single dispatch: 256 blocks x 1024 threads, exactly 1 block/CU
    // (16 waves <= 32, 64KB LDS <= 160KB, VGPR <= 128 via launch_bounds)
    // -> all blocks co-resident; internal spin barriers cannot deadlock.
    // All generation slots start from harness poison (negative as int).
    k_fused<<<NBLK, NT, 0, stream>>>(inputs, states, tau, bias, erev, wgt,
                                     sigma, mu, serev, swgt, ssigma, smu,
                                     mask, smask, inw, inb, outw, outb,
                                     out, ws);
}